// Round 1
// baseline (10044.325 us; speedup 1.0000x reference)
//
#include <hip/hip_runtime.h>
#include <hip/hip_bf16.h>
#include <math.h>

using bf16 = __hip_bfloat16;

constexpr int B  = 1024;
constexpr int NN = 128;   // nodes per tree
constexpr int F  = 318;   // raw features
constexpr int E  = 109;   // encoder out channels
constexpr int O1 = 512, O2 = 256, O3 = 128;

// ---------------- weight pre-transpose ----------------
// enc_w [E][F] -> wTe [F][128] (o padded 109->128 with zeros)
__global__ __launch_bounds__(256) void transpose_enc_w(const float* __restrict__ w,
                                                       float* __restrict__ wT)
{
    int tid = blockIdx.x * 256 + threadIdx.x;
    if (tid >= F * 128) return;
    int c = tid >> 7, o = tid & 127;
    wT[tid] = (o < E) ? w[o * F + c] : 0.f;
}

// w [O][C][3] -> wT [(c*3+k)][O]
__global__ __launch_bounds__(256) void transpose_conv_w(const float* __restrict__ w,
                                                        float* __restrict__ wT,
                                                        int O, int C)
{
    int tid = blockIdx.x * 256 + threadIdx.x;
    int total = O * C * 3;
    if (tid >= total) return;
    int o = tid / (C * 3);
    int r = tid - o * (C * 3);
    int c = r / 3, k = r - c * 3;
    wT[(c * 3 + k) * O + o] = w[tid];
}

// ---------------- encoder: x0[b,o,n] = sum_c enc_w[o,c]*trees[b,c,n] + enc_b[o] ----------------
__global__ __launch_bounds__(256) void enc_kernel(const float* __restrict__ trees,
                                                  const float* __restrict__ wT,   // [F][128]
                                                  const float* __restrict__ bias, // [E]
                                                  bf16* __restrict__ x0)          // [B][E][NN]
{
    const int b = blockIdx.x;
    const int tid = threadIdx.x;
    const int n = tid & (NN - 1);
    const int h = tid >> 7;  // 0/1
    const float* tb = trees + (size_t)b * F * NN;
    for (int p = 0; p < 2; ++p) {
        const int obase = p * 64 + h * 32;
        float acc[32];
#pragma unroll
        for (int i = 0; i < 32; ++i) acc[i] = 0.f;
        for (int c = 0; c < F; ++c) {
            const float xv = tb[c * NN + n];
            const float* w = wT + c * 128 + obase;
#pragma unroll
            for (int oi = 0; oi < 32; ++oi) acc[oi] += w[oi] * xv;
        }
#pragma unroll
        for (int oi = 0; oi < 32; ++oi) {
            const int o = obase + oi;
            if (o < E)
                x0[(size_t)b * E * NN + (size_t)o * NN + n] = __float2bfloat16(acc[oi] + bias[o]);
        }
    }
}

// ---------------- tree conv (+ folded norm/relu of previous layer on load) ----------------
// y[b,o,n] = bias[o] + sum_c sum_k w[o,c,k] * T(x[b, c, idx[b,3n+k]])
// where T(v) = NORM ? max(v-mu,0)*inv : v
template <int CIN, int COUT, int XC, bool NORM>
__global__ __launch_bounds__(256) void conv_kernel(const bf16* __restrict__ xin,  // [B][CIN][NN]
                                                   const int* __restrict__ idx,   // [B][3*NN]
                                                   const float* __restrict__ wT,  // [(CIN*3)][COUT]
                                                   const float* __restrict__ bias,
                                                   const float* __restrict__ stats, // {mu, inv}
                                                   bf16* __restrict__ yout,         // [B][COUT][NN]
                                                   float* __restrict__ partials)    // [B][2]
{
    __shared__ float xs[XC][NN];
    const int b = blockIdx.x;
    const int tid = threadIdx.x;
    const int n = tid & (NN - 1);
    const int h = tid >> 7;
    float mu = 0.f, inv = 1.f;
    if (NORM) { mu = stats[0]; inv = stats[1]; }
    const int* idb = idx + b * 3 * NN;
    const int i0 = idb[3 * n + 0], i1 = idb[3 * n + 1], i2 = idb[3 * n + 2];
    const bf16* xb = xin + (size_t)b * CIN * NN;
    constexpr int NCH = (CIN + XC - 1) / XC;
    constexpr int NPASS = COUT / 64;
    float tsum = 0.f, tss = 0.f;
    for (int p = 0; p < NPASS; ++p) {
        float acc[32];
#pragma unroll
        for (int i = 0; i < 32; ++i) acc[i] = 0.f;
        const int obase = p * 64 + h * 32;
        for (int ch = 0; ch < NCH; ++ch) {
            const int c0 = ch * XC;
            int rows = CIN - c0; if (rows > XC) rows = XC;
            if (!(NCH == 1 && p > 0)) {   // if whole x fits, stage once
                __syncthreads();
                for (int e = tid; e < rows * NN; e += 256) {
                    const int r = e >> 7, cc = e & (NN - 1);
                    float v = __bfloat162float(xb[(size_t)(c0 + r) * NN + cc]);
                    if (NORM) v = fmaxf(v - mu, 0.f) * inv;
                    xs[r][cc] = v;
                }
                __syncthreads();
            }
            for (int c = 0; c < rows; ++c) {
                const float xv0 = xs[c][i0];
                const float xv1 = xs[c][i1];
                const float xv2 = xs[c][i2];
                const float* w0 = wT + (size_t)((c0 + c) * 3 + 0) * COUT + obase;
                const float* w1 = w0 + COUT;
                const float* w2 = w1 + COUT;
#pragma unroll
                for (int oi = 0; oi < 32; ++oi)
                    acc[oi] += w0[oi] * xv0 + w1[oi] * xv1 + w2[oi] * xv2;
            }
        }
#pragma unroll
        for (int oi = 0; oi < 32; ++oi) {
            const int o = obase + oi;
            const float v = acc[oi] + bias[o];
            tsum += v;
            tss += v * v;
            yout[(size_t)b * COUT * NN + (size_t)o * NN + n] = __float2bfloat16(v);
        }
    }
    // block reduction of (sum, sumsq) -> partials[b]
    __syncthreads();
    float* red = &xs[0][0];
    red[tid] = tsum;
    red[256 + tid] = tss;
    __syncthreads();
    for (int s = 128; s > 0; s >>= 1) {
        if (tid < s) { red[tid] += red[tid + s]; red[256 + tid] += red[256 + tid + s]; }
        __syncthreads();
    }
    if (tid == 0) { partials[2 * b] = red[0]; partials[2 * b + 1] = red[256]; }
}

// ---------------- finalize global layernorm stats ----------------
__global__ __launch_bounds__(256) void stats_kernel(const float* __restrict__ partials,
                                                    float* __restrict__ stats,
                                                    double ntot)
{
    __shared__ double sd[256], sd2[256];
    double s = 0.0, s2 = 0.0;
    for (int i = threadIdx.x; i < B; i += 256) { s += (double)partials[2 * i]; s2 += (double)partials[2 * i + 1]; }
    sd[threadIdx.x] = s; sd2[threadIdx.x] = s2;
    __syncthreads();
    for (int k = 128; k > 0; k >>= 1) {
        if (threadIdx.x < k) { sd[threadIdx.x] += sd[threadIdx.x + k]; sd2[threadIdx.x] += sd2[threadIdx.x + k]; }
        __syncthreads();
    }
    if (threadIdx.x == 0) {
        double mu = sd[0] / ntot;
        double var = (sd2[0] - sd[0] * sd[0] / ntot) / (ntot - 1.0);
        double sdv = sqrt(var > 0.0 ? var : 0.0);
        stats[0] = (float)mu;
        stats[1] = (float)(1.0 / (sdv + 1e-5));
    }
}

// ---------------- pooling + both heads ----------------
// pooled[b,o] = relu((max_n y3[b,o,n] - mu)*inv); out = sigmoid(pooled . w + b)
__global__ __launch_bounds__(128) void pool_head_kernel(const bf16* __restrict__ y3,
                                                        const float* __restrict__ stats,
                                                        const float* __restrict__ latw,
                                                        const float* __restrict__ latb,
                                                        const float* __restrict__ costw,
                                                        const float* __restrict__ costb,
                                                        float* __restrict__ out)
{
    const int b = blockIdx.x, t = threadIdx.x;
    const float mu = stats[0], inv = stats[1];
    const bf16* row = y3 + ((size_t)b * 128 + t) * NN;
    float m = -1e30f;
    for (int n = 0; n < NN; ++n) m = fmaxf(m, __bfloat162float(row[n]));
    const float pooled = fmaxf((m - mu) * inv, 0.f);
    __shared__ float pl[128];
    pl[t] = pooled;
    __syncthreads();
    const float* w = (t < 64) ? latw : costw;
    const int l = t & 63;
    float v = pl[l] * w[l] + pl[l + 64] * w[l + 64];
    for (int s = 32; s > 0; s >>= 1) v += __shfl_down(v, s);
    if (l == 0) {
        const float bb = (t < 64) ? latb[0] : costb[0];
        out[(t < 64 ? 0 : B) + b] = 1.f / (1.f + expf(-(v + bb)));
    }
}

// ---------------- launch ----------------
extern "C" void kernel_launch(void* const* d_in, const int* in_sizes, int n_in,
                              void* d_out, int out_size, void* d_ws, size_t ws_size,
                              hipStream_t stream)
{
    (void)in_sizes; (void)n_in; (void)out_size; (void)ws_size;
    const float* trees   = (const float*)d_in[0];
    const int*   indexes = (const int*)  d_in[1];
    const float* enc_w   = (const float*)d_in[2];
    const float* enc_b   = (const float*)d_in[3];
    const float* w1 = (const float*)d_in[4];
    const float* b1 = (const float*)d_in[5];
    const float* w2 = (const float*)d_in[6];
    const float* b2 = (const float*)d_in[7];
    const float* w3 = (const float*)d_in[8];
    const float* b3 = (const float*)d_in[9];
    const float* lat_w  = (const float*)d_in[10];
    const float* lat_b  = (const float*)d_in[11];
    const float* cost_w = (const float*)d_in[12];
    const float* cost_b = (const float*)d_in[13];
    float* out = (float*)d_out;

    char* ws = (char*)d_ws;
    size_t off = 0;
    auto alloc = [&](size_t bytes) -> void* {
        void* p = (void*)(ws + off);
        off += (bytes + 255) & ~(size_t)255;
        return p;
    };
    float* wTe = (float*)alloc((size_t)F * 128 * 4);
    float* wT1 = (float*)alloc((size_t)E  * 3 * O1 * 4);
    float* wT2 = (float*)alloc((size_t)O1 * 3 * O2 * 4);
    float* wT3 = (float*)alloc((size_t)O2 * 3 * O3 * 4);
    bf16* x0 = (bf16*)alloc((size_t)B * E  * NN * 2);
    bf16* y1 = (bf16*)alloc((size_t)B * O1 * NN * 2);
    bf16* y2 = (bf16*)alloc((size_t)B * O2 * NN * 2);
    bf16* y3 = (bf16*)alloc((size_t)B * O3 * NN * 2);
    float* partials = (float*)alloc((size_t)B * 2 * 4);
    float* stats    = (float*)alloc(6 * 4);

    transpose_enc_w<<<dim3((F * 128 + 255) / 256), dim3(256), 0, stream>>>(enc_w, wTe);
    transpose_conv_w<<<dim3((O1 * E  * 3 + 255) / 256), dim3(256), 0, stream>>>(w1, wT1, O1, E);
    transpose_conv_w<<<dim3((O2 * O1 * 3 + 255) / 256), dim3(256), 0, stream>>>(w2, wT2, O2, O1);
    transpose_conv_w<<<dim3((O3 * O2 * 3 + 255) / 256), dim3(256), 0, stream>>>(w3, wT3, O3, O2);

    enc_kernel<<<dim3(B), dim3(256), 0, stream>>>(trees, wTe, enc_b, x0);

    conv_kernel<E, O1, 109, false><<<dim3(B), dim3(256), 0, stream>>>(x0, indexes, wT1, b1, nullptr, y1, partials);
    stats_kernel<<<dim3(1), dim3(256), 0, stream>>>(partials, stats + 0, (double)((size_t)B * O1 * NN));

    conv_kernel<O1, O2, 128, true><<<dim3(B), dim3(256), 0, stream>>>(y1, indexes, wT2, b2, stats + 0, y2, partials);
    stats_kernel<<<dim3(1), dim3(256), 0, stream>>>(partials, stats + 2, (double)((size_t)B * O2 * NN));

    conv_kernel<O2, O3, 128, true><<<dim3(B), dim3(256), 0, stream>>>(y2, indexes, wT3, b3, stats + 2, y3, partials);
    stats_kernel<<<dim3(1), dim3(256), 0, stream>>>(partials, stats + 4, (double)((size_t)B * O3 * NN));

    pool_head_kernel<<<dim3(B), dim3(128), 0, stream>>>(y3, stats + 4, lat_w, lat_b, cost_w, cost_b, out);
}

// Round 2
// 541.599 us; speedup vs baseline: 18.5457x; 18.5457x over previous
//
#include <hip/hip_runtime.h>
#include <hip/hip_bf16.h>
#include <math.h>

using short8 = __attribute__((ext_vector_type(8))) short;
using f32x4  = __attribute__((ext_vector_type(4))) float;

constexpr int B  = 1024;
constexpr int NN = 128;   // nodes per tree
constexpr int F  = 318;   // raw features

__device__ inline float bf2f(unsigned short u) {
    union { unsigned int i; float f; } x; x.i = ((unsigned int)u) << 16; return x.f;
}
__device__ inline unsigned short f2bf(float f) {
    union { float f; unsigned int i; } x; x.f = f;
    unsigned int r = x.i + 0x7fff + ((x.i >> 16) & 1);
    return (unsigned short)(r >> 16);
}

// ---------- trees [B][F][NN] f32 -> treesT [B][NN][320] bf16 (zero-pad c>=318) ----------
__global__ __launch_bounds__(256) void transpose_trees(const float* __restrict__ trees,
                                                       unsigned short* __restrict__ treesT)
{
    __shared__ float tile[32][129];
    const int b = blockIdx.x;
    const int c0 = blockIdx.y * 32;
#pragma unroll
    for (int i = 0; i < 16; ++i) {
        int e = threadIdx.x + i * 256;        // 32*128 = 4096
        int c = e >> 7, n = e & 127;
        float v = (c0 + c < F) ? trees[((size_t)b * F + c0 + c) * NN + n] : 0.f;
        tile[c][n] = v;
    }
    __syncthreads();
    const int n = threadIdx.x >> 1;
    const int ch = (threadIdx.x & 1) * 16;
    unsigned int out[8];
#pragma unroll
    for (int i = 0; i < 8; ++i) {
        float a = tile[ch + 2 * i][n];
        float bb = tile[ch + 2 * i + 1][n];
        out[i] = (unsigned int)f2bf(a) | ((unsigned int)f2bf(bb) << 16);
    }
    unsigned short* dst = treesT + ((size_t)b * NN + n) * 320 + c0 + ch;
    reinterpret_cast<uint4*>(dst)[0] = make_uint4(out[0], out[1], out[2], out[3]);
    reinterpret_cast<uint4*>(dst)[1] = make_uint4(out[4], out[5], out[6], out[7]);
}

// ---------- weight prepack into MFMA B-fragment order ----------
// packed element t = ((kb*(COUT/16)+ob)*64+lane)*8+j  -> weight for K-index, out-col o
// K order: kb = (chunk*KMUL + k)*(CC/32) + ks ; c = chunk*CC + ks*32 + (lane>>4)*8 + j ; o = ob*16 + (lane&15)
__global__ __launch_bounds__(256) void prepack_w(const float* __restrict__ w,
                                                 unsigned short* __restrict__ wp,
                                                 int kmul, int OREAL, int CREAL,
                                                 int CC, int COUT, int KTOT)
{
    int t = blockIdx.x * 256 + threadIdx.x;
    if (t >= KTOT * COUT) return;
    int j = t & 7;
    int lane = (t >> 3) & 63;
    int rest = t >> 9;
    int obn = COUT / 16;
    int ob = rest % obn;
    int kb = rest / obn;
    int S = kmul * (CC / 32);
    int ch = kb / S;
    int rem = kb % S;
    int k = rem / (CC / 32);
    int ks = rem % (CC / 32);
    int c = ch * CC + ks * 32 + (lane >> 4) * 8 + j;
    int o = ob * 16 + (lane & 15);
    float v = 0.f;
    if (c < CREAL && o < OREAL)
        v = (kmul == 3) ? w[((size_t)o * CREAL + c) * 3 + k] : w[(size_t)o * CREAL + c];
    wp[t] = f2bf(v);
}

// ---------- unified GEMM (+gather, +folded norm/relu on load, +stats) ----------
// out[b][n][o] = bias[o] + sum_K A[n][K] * Wp[K][o]
// GATHER: A row for K-plane k = T(x[b][ idx[b][3n+k] ][c]) ; else A[n][c]=T(x[b][n][c])
// T(v) = NORM ? max(v-mu,0)*inv : v
template <int CINP, int KMUL, int COUT, int CC, int OREAL, bool GATHER, bool NORM, bool STATS>
__global__ __launch_bounds__(256) void gemm_tree(const unsigned short* __restrict__ xin, // [B][NN][CINP]
                                                 const int* __restrict__ idx,            // [B][3*NN]
                                                 const unsigned short* __restrict__ wp,
                                                 const float* __restrict__ bias,
                                                 const float* __restrict__ stats,
                                                 unsigned short* __restrict__ yout,      // [B][NN][COUT]
                                                 float* __restrict__ partials)
{
    constexpr int NCH = CINP / CC;
    constexpr int KSN = CC / 32;
    __shared__ __align__(16) unsigned short xs[NN * CC];
    __shared__ float rbuf[8];

    const int b = blockIdx.x;
    const int ot = blockIdx.y;                 // o-tile base = ot*128
    const int tid = threadIdx.x;
    const int lane = tid & 63;
    const int wv = tid >> 6;
    const int wm = wv >> 1, wn = wv & 1;
    const int l15 = lane & 15, lh = lane >> 4;

    float mu = 0.f, inv = 1.f;
    if (NORM) { mu = stats[0]; inv = stats[1]; }

    int srcs[4][GATHER ? 3 : 1];
#pragma unroll
    for (int mf = 0; mf < 4; ++mf) {
        int node = wm * 64 + mf * 16 + l15;
        if (GATHER) {
#pragma unroll
            for (int k = 0; k < 3; ++k) srcs[mf][k] = idx[b * 3 * NN + 3 * node + k];
        } else {
            srcs[mf][0] = node;
        }
    }

    f32x4 acc[16];
#pragma unroll
    for (int i = 0; i < 16; ++i) acc[i] = (f32x4)0.f;

    for (int ch = 0; ch < NCH; ++ch) {
        __syncthreads();
#pragma unroll
        for (int i = 0; i < (NN * CC) / (256 * 8); ++i) {
            int e = (tid + i * 256) * 8;
            int n = e / CC, cl = e % CC;
            uint4 v = *reinterpret_cast<const uint4*>(xin + ((size_t)b * NN + n) * CINP + ch * CC + cl);
            if (NORM) {
                unsigned int vv[4] = {v.x, v.y, v.z, v.w};
#pragma unroll
                for (int q = 0; q < 4; ++q) {
                    float f0 = fmaxf(bf2f((unsigned short)(vv[q] & 0xffff)) - mu, 0.f) * inv;
                    float f1 = fmaxf(bf2f((unsigned short)(vv[q] >> 16)) - mu, 0.f) * inv;
                    vv[q] = (unsigned int)f2bf(f0) | ((unsigned int)f2bf(f1) << 16);
                }
                v = make_uint4(vv[0], vv[1], vv[2], vv[3]);
            }
            int byte = n * (CC * 2) + cl * 2;
            byte ^= ((n & 7) << 4);
            *reinterpret_cast<uint4*>(reinterpret_cast<char*>(xs) + byte) = v;
        }
        __syncthreads();
#pragma unroll
        for (int k = 0; k < KMUL; ++k) {
#pragma unroll
            for (int ks = 0; ks < KSN; ++ks) {
                const int kb = (ch * KMUL + k) * KSN + ks;
                short8 af[4], bfr[4];
#pragma unroll
                for (int mf = 0; mf < 4; ++mf) {
                    int sn = srcs[mf][GATHER ? k : 0];
                    int byte = sn * (CC * 2) + (ks * 32 + lh * 8) * 2;
                    byte ^= ((sn & 7) << 4);
                    af[mf] = *reinterpret_cast<const short8*>(reinterpret_cast<const char*>(xs) + byte);
                }
#pragma unroll
                for (int nf = 0; nf < 4; ++nf) {
                    const int ob = ot * 8 + wn * 4 + nf;
                    bfr[nf] = *reinterpret_cast<const short8*>(wp + (((size_t)kb * (COUT / 16) + ob) * 64 + lane) * 8);
                }
#pragma unroll
                for (int mf = 0; mf < 4; ++mf)
#pragma unroll
                    for (int nf = 0; nf < 4; ++nf)
                        acc[mf * 4 + nf] = __builtin_amdgcn_mfma_f32_16x16x32_bf16(af[mf], bfr[nf], acc[mf * 4 + nf], 0, 0, 0);
            }
        }
    }

    // epilogue: bias, stats, coalesced store via LDS
    float bs[4];
#pragma unroll
    for (int nf = 0; nf < 4; ++nf) {
        int o = ot * 128 + wn * 64 + nf * 16 + l15;
        bs[nf] = (o < OREAL) ? bias[o] : 0.f;
    }
    float tsum = 0.f, tss = 0.f;
    __syncthreads();
#pragma unroll
    for (int mf = 0; mf < 4; ++mf) {
#pragma unroll
        for (int nf = 0; nf < 4; ++nf) {
#pragma unroll
            for (int r = 0; r < 4; ++r) {
                float v = acc[mf * 4 + nf][r] + bs[nf];
                if (STATS) { tsum += v; tss += v * v; }
                int row = wm * 64 + mf * 16 + lh * 4 + r;
                int col = wn * 64 + nf * 16 + l15;
                xs[row * 128 + col] = f2bf(v);
            }
        }
    }
    __syncthreads();
#pragma unroll
    for (int i = 0; i < 8; ++i) {
        int e = tid + i * 256;            // 16B units, 2048 total
        int n = e >> 4, o = (e & 15) * 8;
        uint4 v = *reinterpret_cast<const uint4*>(xs + n * 128 + o);
        *reinterpret_cast<uint4*>(yout + ((size_t)b * NN + n) * COUT + ot * 128 + o) = v;
    }

    if (STATS) {
#pragma unroll
        for (int s = 32; s; s >>= 1) { tsum += __shfl_down(tsum, s); tss += __shfl_down(tss, s); }
        if (lane == 0) { rbuf[wv * 2] = tsum; rbuf[wv * 2 + 1] = tss; }
        __syncthreads();
        if (tid == 0) {
            float s = rbuf[0] + rbuf[2] + rbuf[4] + rbuf[6];
            float q = rbuf[1] + rbuf[3] + rbuf[5] + rbuf[7];
            int gid = blockIdx.y * gridDim.x + blockIdx.x;
            partials[2 * gid] = s;
            partials[2 * gid + 1] = q;
        }
    }
}

// ---------- finalize global layernorm stats ----------
__global__ __launch_bounds__(256) void stats_kernel(const float* __restrict__ partials,
                                                    float* __restrict__ stats,
                                                    int npart, double ntot)
{
    __shared__ double sd[256], sd2[256];
    double s = 0.0, s2 = 0.0;
    for (int i = threadIdx.x; i < npart; i += 256) { s += (double)partials[2 * i]; s2 += (double)partials[2 * i + 1]; }
    sd[threadIdx.x] = s; sd2[threadIdx.x] = s2;
    __syncthreads();
    for (int k = 128; k > 0; k >>= 1) {
        if (threadIdx.x < k) { sd[threadIdx.x] += sd[threadIdx.x + k]; sd2[threadIdx.x] += sd2[threadIdx.x + k]; }
        __syncthreads();
    }
    if (threadIdx.x == 0) {
        double mu = sd[0] / ntot;
        double var = (sd2[0] - sd[0] * sd[0] / ntot) / (ntot - 1.0);
        double sdv = sqrt(var > 0.0 ? var : 0.0);
        stats[0] = (float)mu;
        stats[1] = (float)(1.0 / (sdv + 1e-5));
    }
}

// ---------- pooling + both heads ----------
__global__ __launch_bounds__(128) void pool_head_kernel(const unsigned short* __restrict__ y3, // [B][NN][128]
                                                        const float* __restrict__ stats,
                                                        const float* __restrict__ latw,
                                                        const float* __restrict__ latb,
                                                        const float* __restrict__ costw,
                                                        const float* __restrict__ costb,
                                                        float* __restrict__ out)
{
    const int b = blockIdx.x, t = threadIdx.x;
    const float mu = stats[0], inv = stats[1];
    const unsigned short* base = y3 + (size_t)b * NN * 128 + t;
    float m = -1e30f;
    for (int n = 0; n < NN; ++n) m = fmaxf(m, bf2f(base[n * 128]));
    const float pooled = fmaxf((m - mu) * inv, 0.f);
    __shared__ float pl[128];
    pl[t] = pooled;
    __syncthreads();
    const float* w = (t < 64) ? latw : costw;
    const int l = t & 63;
    float v = pl[l] * w[l] + pl[l + 64] * w[l + 64];
    for (int s = 32; s > 0; s >>= 1) v += __shfl_down(v, s);
    if (l == 0) {
        const float bb = (t < 64) ? latb[0] : costb[0];
        out[(t < 64 ? 0 : B) + b] = 1.f / (1.f + expf(-(v + bb)));
    }
}

// ---------- launch ----------
extern "C" void kernel_launch(void* const* d_in, const int* in_sizes, int n_in,
                              void* d_out, int out_size, void* d_ws, size_t ws_size,
                              hipStream_t stream)
{
    (void)in_sizes; (void)n_in; (void)out_size; (void)ws_size;
    const float* trees   = (const float*)d_in[0];
    const int*   indexes = (const int*)  d_in[1];
    const float* enc_w   = (const float*)d_in[2];
    const float* enc_b   = (const float*)d_in[3];
    const float* w1 = (const float*)d_in[4];
    const float* b1 = (const float*)d_in[5];
    const float* w2 = (const float*)d_in[6];
    const float* b2 = (const float*)d_in[7];
    const float* w3 = (const float*)d_in[8];
    const float* b3 = (const float*)d_in[9];
    const float* lat_w  = (const float*)d_in[10];
    const float* lat_b  = (const float*)d_in[11];
    const float* cost_w = (const float*)d_in[12];
    const float* cost_b = (const float*)d_in[13];
    float* out = (float*)d_out;

    char* ws = (char*)d_ws;
    size_t off = 0;
    auto alloc = [&](size_t bytes) -> char* {
        char* p = ws + off;
        off += (bytes + 255) & ~(size_t)255;
        return p;
    };
    unsigned short* wpe = (unsigned short*)alloc((size_t)320 * 128 * 2);
    unsigned short* wp1 = (unsigned short*)alloc((size_t)384 * 512 * 2);
    unsigned short* wp2 = (unsigned short*)alloc((size_t)1536 * 256 * 2);
    unsigned short* wp3 = (unsigned short*)alloc((size_t)768 * 128 * 2);
    unsigned short* x0  = (unsigned short*)alloc((size_t)B * NN * 128 * 2);
    unsigned short* y1  = (unsigned short*)alloc((size_t)B * NN * 512 * 2);
    // region R: treesT (83.9MB) aliases y2+y3 (100.6MB) — treesT dead after enc
    char* R = alloc((size_t)B * NN * (256 + 128) * 2);
    unsigned short* treesT = (unsigned short*)R;             // [B][NN][320]
    unsigned short* y2     = (unsigned short*)R;             // [B][NN][256]
    unsigned short* y3     = (unsigned short*)(R + (size_t)B * NN * 256 * 2);
    float* partials = (float*)alloc((size_t)4096 * 2 * 4);
    float* stats    = (float*)alloc(8 * 4);

    transpose_trees<<<dim3(B, 10), dim3(256), 0, stream>>>(trees, treesT);

    prepack_w<<<dim3((320 * 128 + 255) / 256),  dim3(256), 0, stream>>>(enc_w, wpe, 1, 109, 318, 160, 128, 320);
    prepack_w<<<dim3((384 * 512 + 255) / 256),  dim3(256), 0, stream>>>(w1, wp1, 3, 512, 109, 128, 512, 384);
    prepack_w<<<dim3((1536 * 256 + 255) / 256), dim3(256), 0, stream>>>(w2, wp2, 3, 256, 512, 128, 256, 1536);
    prepack_w<<<dim3((768 * 128 + 255) / 256),  dim3(256), 0, stream>>>(w3, wp3, 3, 128, 256, 128, 128, 768);

    // encoder: [B][NN][320] @ [320][128] -> x0 [B][NN][128]
    gemm_tree<320, 1, 128, 160, 109, false, false, false>
        <<<dim3(B, 1), dim3(256), 0, stream>>>(treesT, indexes, wpe, enc_b, stats, x0, partials);

    // conv1: gather(x0) [B][NN][3*128] @ [384][512] -> y1
    gemm_tree<128, 3, 512, 128, 512, true, false, true>
        <<<dim3(B, 4), dim3(256), 0, stream>>>(x0, indexes, wp1, b1, stats, y1, partials);
    stats_kernel<<<dim3(1), dim3(256), 0, stream>>>(partials, stats + 0, 4096, (double)((size_t)B * 512 * NN));

    // conv2
    gemm_tree<512, 3, 256, 128, 256, true, true, true>
        <<<dim3(B, 2), dim3(256), 0, stream>>>(y1, indexes, wp2, b2, stats + 0, y2, partials);
    stats_kernel<<<dim3(1), dim3(256), 0, stream>>>(partials, stats + 2, 2048, (double)((size_t)B * 256 * NN));

    // conv3
    gemm_tree<256, 3, 128, 128, 128, true, true, true>
        <<<dim3(B, 1), dim3(256), 0, stream>>>(y2, indexes, wp3, b3, stats + 2, y3, partials);
    stats_kernel<<<dim3(1), dim3(256), 0, stream>>>(partials, stats + 4, 1024, (double)((size_t)B * 128 * NN));

    pool_head_kernel<<<dim3(B), dim3(128), 0, stream>>>(y3, stats + 4, lat_w, lat_b, cost_w, cost_b, out);
}